// Round 1
// 295.483 us; speedup vs baseline: 1.0175x; 1.0175x over previous
//
#include <hip/hip_runtime.h>

#define B_ 16
#define S_ 20
#define L_ 64
#define T_ 1280
#define H_ 768
#define NITEMS 50000
#define TEMP 0.05f
#define EPSN 1e-8f

#define BM 320
#define BN 128
#define BK 32
#define NKT (H_ / BK)  // 24

typedef __attribute__((ext_vector_type(8))) short short8;
typedef __attribute__((ext_vector_type(4))) short short4v;
typedef __attribute__((ext_vector_type(4))) float f32x4;

// float -> bf16 (round-to-nearest-even)
__device__ __forceinline__ unsigned short f2bf(float f) {
    unsigned int u = __float_as_uint(f);
    u = u + 0x7FFFu + ((u >> 16) & 1u);
    return (unsigned short)(u >> 16);
}

// async global->LDS, 16B per lane. LDS dest must be wave-uniform base + lane*16.
typedef __attribute__((address_space(3))) void lds_void;
typedef const __attribute__((address_space(1))) void gbl_void;
__device__ __forceinline__ void load_lds16(const void* g, void* l) {
    __builtin_amdgcn_global_load_lds((gbl_void*)g, (lds_void*)l, 16, 0, 0);
}

// ---------------------------------------------------------------------------
// Kernel 1: per-(b,s) nan-mean pool, normalize, fold 1/(pn*TEMP), write bf16.
// NEW: output layout is XOR-swizzled within each 32-col (64B) k-chunk:
// logical 8-short slot q lands at slot q^(row&3). gemm stages rows linearly
// via global_load_lds (which cannot scatter) and de-swizzles at fragment
// read -> bank-conflict-free ds_read_b128 without breaking the async copy.
// ---------------------------------------------------------------------------
__global__ __launch_bounds__(192) void pool_kernel(const float* __restrict__ hidden,
                                                   const int* __restrict__ pos,
                                                   unsigned short* __restrict__ A,
                                                   int* __restrict__ valid) {
    const int row = blockIdx.x;  // 0..319
    const int b = row / S_, s = row % S_;
    const int tid = threadIdx.x;  // 0..191; thread owns 4 consecutive h-cols

    __shared__ float wgt[L_];
    __shared__ int cntS;
    __shared__ float red[3];

    const int* pbase = pos + b * T_ + s * L_;
    if (tid < L_) {
        const int match = (pbase[tid] == s + 1) ? 1 : 0;
        unsigned long long bal = __ballot(match);
        wgt[tid] = match ? 1.0f : 0.0f;
        if (tid == 0) cntS = (int)__popcll(bal);
    }
    __syncthreads();

    const int cnt = cntS;
    const float inv = 1.0f / (float)(cnt > 0 ? cnt : 1);
    const float* hbase = hidden + ((size_t)b * T_ + (size_t)s * L_) * H_ + tid * 4;

    float a0 = 0.f, a1 = 0.f, a2 = 0.f, a3 = 0.f;
#pragma unroll 8
    for (int t = 0; t < L_; ++t) {
        const float w = wgt[t];
        const float4 v = *reinterpret_cast<const float4*>(hbase + (size_t)t * H_);
        a0 += w * v.x; a1 += w * v.y; a2 += w * v.z; a3 += w * v.w;
    }
    a0 *= inv; a1 *= inv; a2 *= inv; a3 *= inv;

    // sum of squares over 768 cols (3 waves)
    float ss = a0 * a0 + a1 * a1 + a2 * a2 + a3 * a3;
#pragma unroll
    for (int off = 32; off; off >>= 1) ss += __shfl_xor(ss, off, 64);
    const int wave = tid >> 6, lane = tid & 63;
    if (lane == 0) red[wave] = ss;
    __syncthreads();
    const float tot = red[0] + red[1] + red[2];
    const float scale = 1.0f / (fmaxf(sqrtf(tot), EPSN) * TEMP);

    short4v w4;
    w4[0] = (short)f2bf(a0 * scale);
    w4[1] = (short)f2bf(a1 * scale);
    w4[2] = (short)f2bf(a2 * scale);
    w4[3] = (short)f2bf(a3 * scale);
    // swizzled store: thread owns logical slot tid>>1 (8 shorts), half tid&1
    const int slot = tid >> 1;
    const int slotSw = (slot & ~3) | ((slot & 3) ^ (row & 3));
    *reinterpret_cast<short4v*>(A + (size_t)row * H_ + slotSw * 8 + (tid & 1) * 4) = w4;
    if (tid == 0) valid[row] = (cnt > 0) ? 1 : 0;
}

// ---------------------------------------------------------------------------
// Kernel 2: full-M GEMM, restructured to minimize LDS traffic per FLOP.
//  - wave w owns rows [80w,80w+80) x all 128 cols (5x8 frags = 40 MFMA/iter):
//    the A tile is read from LDS exactly ONCE per iter across the block
//    (was 4x: every wave re-read all 320 rows).
//  - B staged fp32->regs->bf16 LDS (T14: loads issued at iter top, cvt +
//    ds_write after the MFMA block -> HBM latency hidden under 40 MFMAs).
//    Halves B fragment bytes, Bs footprint 32->16 KB, and en is accumulated
//    in registers during staging (removes the conflicted LDS re-read).
//  - XOR slot-swizzle on As (pre-swizzled in ws by pool_kernel) and Bs
//    (swizzled ds_write), de-swizzled at fragment read: slot = quad^(lq&3).
// LDS/iter/block: 80 KB (was 148). LDS total 57.9 KB -> 2 blocks/CU.
// ---------------------------------------------------------------------------
__global__ __launch_bounds__(256, 2) void gemm_kernel(const float* __restrict__ emb,
                                                      const unsigned short* __restrict__ A,
                                                      const int* __restrict__ valid,
                                                      float* __restrict__ out) {
    const int n0 = blockIdx.x * BN;
    const int tid = threadIdx.x;
    const int wave = tid >> 6, lane = tid & 63, quad = lane >> 4, lq = lane & 15;

    __shared__ alignas(16) short As[2][BM * BK];  // 2 x 20 KB bf16 (swizzled content)
    __shared__ alignas(16) short Bs[2][BN * BK];  // 2 x  8 KB bf16 (swizzled slots)
    __shared__ float sEn[BN];
    __shared__ int sMask[B_];

    // per-session validity bitmask (20 bits)
    if (tid < B_) {
        int m = 0;
        for (int s = 0; s < S_; ++s) m |= (valid[tid * S_ + s] ? 1 : 0) << s;
        sMask[tid] = m;
    }

    // --- staging geometry ---
    // A: 5 global_load_lds issues; issue i covers row tid/4 + i*64, slot tid&3.
    // ws content is pre-swizzled, so the copy stays linear.
    const unsigned short* aSrc = A + (size_t)(tid >> 2) * H_ + (tid & 3) * 8;
    // B: thread owns n-row tid>>1, 16 fp32 at cols (tid&1)*16 (+k0).
    const int brLoc = tid >> 1;
    int brGlb = n0 + brLoc;
    if (brGlb > NITEMS - 1) brGlb = NITEMS - 1;  // clamp: OOB cols computed, never stored
    const float* bSrc = emb + (size_t)brGlb * H_ + (tid & 1) * 16;
    // swizzled LDS write offsets (in shorts): logical slots 2(tid&1)+{0,1}
    const int bw0 = brLoc * BK + ((((tid & 1) * 2) + 0) ^ (brLoc & 3)) * 8;
    const int bw1 = brLoc * BK + ((((tid & 1) * 2) + 1) ^ (brLoc & 3)) * 8;

    float rowSq = 0.f;

    // --- prologue: stage tile 0 ---
    {
        const float4 v0 = *reinterpret_cast<const float4*>(bSrc);
        const float4 v1 = *reinterpret_cast<const float4*>(bSrc + 4);
        const float4 v2 = *reinterpret_cast<const float4*>(bSrc + 8);
        const float4 v3 = *reinterpret_cast<const float4*>(bSrc + 12);
#pragma unroll
        for (int i = 0; i < 5; ++i)
            load_lds16(aSrc + i * 64 * H_, (char*)(&As[0][0]) + tid * 16 + i * 4096);
        rowSq += v0.x * v0.x + v0.y * v0.y + v0.z * v0.z + v0.w * v0.w;
        rowSq += v1.x * v1.x + v1.y * v1.y + v1.z * v1.z + v1.w * v1.w;
        rowSq += v2.x * v2.x + v2.y * v2.y + v2.z * v2.z + v2.w * v2.w;
        rowSq += v3.x * v3.x + v3.y * v3.y + v3.z * v3.z + v3.w * v3.w;
        short8 lo, hi;
        lo[0] = (short)f2bf(v0.x); lo[1] = (short)f2bf(v0.y);
        lo[2] = (short)f2bf(v0.z); lo[3] = (short)f2bf(v0.w);
        lo[4] = (short)f2bf(v1.x); lo[5] = (short)f2bf(v1.y);
        lo[6] = (short)f2bf(v1.z); lo[7] = (short)f2bf(v1.w);
        hi[0] = (short)f2bf(v2.x); hi[1] = (short)f2bf(v2.y);
        hi[2] = (short)f2bf(v2.z); hi[3] = (short)f2bf(v2.w);
        hi[4] = (short)f2bf(v3.x); hi[5] = (short)f2bf(v3.y);
        hi[6] = (short)f2bf(v3.z); hi[7] = (short)f2bf(v3.w);
        *reinterpret_cast<short8*>(&Bs[0][bw0]) = lo;
        *reinterpret_cast<short8*>(&Bs[0][bw1]) = hi;
    }

    f32x4 acc[5][8];
#pragma unroll
    for (int i = 0; i < 5; ++i)
#pragma unroll
        for (int j = 0; j < 8; ++j) acc[i][j] = (f32x4)0.f;

    __syncthreads();

    int cur = 0;
    for (int kt = 0; kt < NKT; ++kt) {
        // issue next-tile loads FIRST (B->regs before A gload_lds, so the
        // compiler's wait for B regs is vmcnt(5), keeping A loads in flight)
        float4 v0, v1, v2, v3;
        const bool more = (kt + 1 < NKT);
        if (more) {
            const int k0 = (kt + 1) * BK;
            v0 = *reinterpret_cast<const float4*>(bSrc + k0);
            v1 = *reinterpret_cast<const float4*>(bSrc + k0 + 4);
            v2 = *reinterpret_cast<const float4*>(bSrc + k0 + 8);
            v3 = *reinterpret_cast<const float4*>(bSrc + k0 + 12);
#pragma unroll
            for (int i = 0; i < 5; ++i)
                load_lds16(aSrc + k0 + i * 64 * H_,
                           (char*)(&As[cur ^ 1][0]) + tid * 16 + i * 4096);
        }

        // B fragments: all 8 n-frags (shared by all waves), de-swizzled read
        short8 bF[8];
#pragma unroll
        for (int nf = 0; nf < 8; ++nf) {
            const int rB = nf * 16 + lq;
            bF[nf] = *reinterpret_cast<const short8*>(
                &Bs[cur][rB * BK + ((quad ^ (lq & 3)) * 8)]);
        }

        // A fragments (this wave's 80-row slice) + MFMA: 5 m-frags x 8 n-frags
#pragma unroll
        for (int mf = 0; mf < 5; ++mf) {
            const int rA = wave * 80 + mf * 16 + lq;
            const short8 aF = *reinterpret_cast<const short8*>(
                &As[cur][rA * BK + ((quad ^ (lq & 3)) * 8)]);
#pragma unroll
            for (int nf = 0; nf < 8; ++nf)
                acc[mf][nf] =
                    __builtin_amdgcn_mfma_f32_16x16x32_bf16(aF, bF[nf], acc[mf][nf], 0, 0, 0);
        }

        // finish staging tile kt+1: en partials + cvt + swizzled ds_write
        if (more) {
            rowSq += v0.x * v0.x + v0.y * v0.y + v0.z * v0.z + v0.w * v0.w;
            rowSq += v1.x * v1.x + v1.y * v1.y + v1.z * v1.z + v1.w * v1.w;
            rowSq += v2.x * v2.x + v2.y * v2.y + v2.z * v2.z + v2.w * v2.w;
            rowSq += v3.x * v3.x + v3.y * v3.y + v3.z * v3.z + v3.w * v3.w;
            short8 lo, hi;
            lo[0] = (short)f2bf(v0.x); lo[1] = (short)f2bf(v0.y);
            lo[2] = (short)f2bf(v0.z); lo[3] = (short)f2bf(v0.w);
            lo[4] = (short)f2bf(v1.x); lo[5] = (short)f2bf(v1.y);
            lo[6] = (short)f2bf(v1.z); lo[7] = (short)f2bf(v1.w);
            hi[0] = (short)f2bf(v2.x); hi[1] = (short)f2bf(v2.y);
            hi[2] = (short)f2bf(v2.z); hi[3] = (short)f2bf(v2.w);
            hi[4] = (short)f2bf(v3.x); hi[5] = (short)f2bf(v3.y);
            hi[6] = (short)f2bf(v3.z); hi[7] = (short)f2bf(v3.w);
            *reinterpret_cast<short8*>(&Bs[cur ^ 1][bw0]) = lo;
            *reinterpret_cast<short8*>(&Bs[cur ^ 1][bw1]) = hi;
        }
        __syncthreads();
        cur ^= 1;
    }

    // finalize en (two threads per row, accumulated in regs during staging)
    rowSq += __shfl_xor(rowSq, 1, 64);
    if (!(tid & 1)) sEn[brLoc] = fmaxf(sqrtf(rowSq), EPSN);
    __syncthreads();

    // epilogue: wave w owns sessions 4w..4w+3 (80 rows = exactly 4 sessions).
    // C/D layout: col = lane&15 (n), row = quad*4+e (m).
#pragma unroll
    for (int nf = 0; nf < 8; ++nf) {
        const int ncol = nf * 16 + lq;
        const int n = n0 + ncol;
        const float inv_en = 1.0f / sEn[ncol];
#pragma unroll
        for (int bl = 0; bl < 4; ++bl) {
            const int bb = wave * 4 + bl;
            const int msk = sMask[bb];
            const int rLo = bl * S_;  // local row base within this wave's 80-row slice
            float lm = -__builtin_inff();
            const int mfLo = rLo >> 4;
            const int mfHi = (rLo + S_ - 1) >> 4;
#pragma unroll
            for (int mf = mfLo; mf <= mfHi; ++mf)
#pragma unroll
                for (int e = 0; e < 4; ++e) {
                    const int r = mf * 16 + quad * 4 + e;
                    const unsigned off = (unsigned)(r - rLo);
                    const bool ok = (off < (unsigned)S_) && ((msk >> off) & 1);
                    lm = ok ? fmaxf(lm, acc[mf][nf][e]) : lm;
                }
            lm = fmaxf(lm, __shfl_xor(lm, 16, 64));
            lm = fmaxf(lm, __shfl_xor(lm, 32, 64));
            if (quad == 0 && n < NITEMS)
                out[(size_t)bb * NITEMS + n] = lm * inv_en;
        }
    }
}

extern "C" void kernel_launch(void* const* d_in, const int* in_sizes, int n_in,
                              void* d_out, int out_size, void* d_ws, size_t ws_size,
                              hipStream_t stream) {
    const float* hidden = (const float*)d_in[0];   // [16,1280,768] f32
    const float* emb    = (const float*)d_in[1];   // [50000,768] f32
    const int*   pos    = (const int*)d_in[3];     // [16,1280] i32
    float* out = (float*)d_out;                    // [16,50000] f32

    unsigned short* Abf = (unsigned short*)d_ws;               // 320*768 bf16 (swizzled)
    int* valid = (int*)((char*)d_ws + (size_t)320 * 768 * 2);  // 320 ints

    pool_kernel<<<dim3(320), dim3(192), 0, stream>>>(hidden, pos, Abf, valid);
    gemm_kernel<<<dim3((NITEMS + BN - 1) / BN), dim3(256), 0, stream>>>(emb, Abf, valid, out);
}

// Round 2
// 295.291 us; speedup vs baseline: 1.0182x; 1.0006x over previous
//
#include <hip/hip_runtime.h>

#define B_ 16
#define S_ 20
#define L_ 64
#define T_ 1280
#define H_ 768
#define NITEMS 50000
#define TEMP 0.05f
#define EPSN 1e-8f

#define BM 320
#define BN 128
#define BK 32
#define NKT (H_ / BK)  // 24

typedef __attribute__((ext_vector_type(8))) short short8;
typedef __attribute__((ext_vector_type(4))) short short4v;
typedef __attribute__((ext_vector_type(4))) float f32x4;

// float -> bf16 (round-to-nearest-even)
__device__ __forceinline__ unsigned short f2bf(float f) {
    unsigned int u = __float_as_uint(f);
    u = u + 0x7FFFu + ((u >> 16) & 1u);
    return (unsigned short)(u >> 16);
}

// async global->LDS, 16B per lane. LDS dest must be wave-uniform base + lane*16.
typedef __attribute__((address_space(3))) void lds_void;
typedef const __attribute__((address_space(1))) void gbl_void;
__device__ __forceinline__ void load_lds16(const void* g, void* l) {
    __builtin_amdgcn_global_load_lds((gbl_void*)g, (lds_void*)l, 16, 0, 0);
}

// ---------------------------------------------------------------------------
// Kernel 1: per-(b,s) nan-mean pool, normalize, fold 1/(pn*TEMP), write bf16.
// 384 threads (float2/lane): 6 waves/block -> ~7.5 waves/CU (was 3.75) since
// this kernel is latency-bound at grid=320.
// Output slot-swizzle: logical 16B-slot q of row r stored at q ^ ((r>>1)&3)
// within each 32-col chunk -> gemm's ds_read_b128 frag reads are uniform
// 2-way (free); gemm stages ws linearly via global_load_lds.
// ---------------------------------------------------------------------------
__global__ __launch_bounds__(384) void pool_kernel(const float* __restrict__ hidden,
                                                   const int* __restrict__ pos,
                                                   unsigned short* __restrict__ A,
                                                   int* __restrict__ valid) {
    const int row = blockIdx.x;  // 0..319
    const int b = row / S_, s = row % S_;
    const int tid = threadIdx.x;  // 0..383; thread owns cols 2*tid, 2*tid+1

    __shared__ float wgt[L_];
    __shared__ int cntS;
    __shared__ float red[6];

    const int* pbase = pos + b * T_ + s * L_;
    if (tid < L_) {  // exactly wave 0
        const int match = (pbase[tid] == s + 1) ? 1 : 0;
        unsigned long long bal = __ballot(match);
        wgt[tid] = match ? 1.0f : 0.0f;
        if (tid == 0) cntS = (int)__popcll(bal);
    }
    __syncthreads();

    const int cnt = cntS;
    const float inv = 1.0f / (float)(cnt > 0 ? cnt : 1);
    const float* hbase = hidden + ((size_t)b * T_ + (size_t)s * L_) * H_ + tid * 2;

    float a0 = 0.f, a1 = 0.f;
#pragma unroll 8
    for (int t = 0; t < L_; ++t) {
        const float w = wgt[t];
        const float2 v = *reinterpret_cast<const float2*>(hbase + (size_t)t * H_);
        a0 += w * v.x; a1 += w * v.y;
    }
    a0 *= inv; a1 *= inv;

    // sum of squares over 768 cols (6 waves)
    float ss = a0 * a0 + a1 * a1;
#pragma unroll
    for (int off = 32; off; off >>= 1) ss += __shfl_xor(ss, off, 64);
    const int wave = tid >> 6, lane = tid & 63;
    if (lane == 0) red[wave] = ss;
    __syncthreads();
    const float tot = red[0] + red[1] + red[2] + red[3] + red[4] + red[5];
    const float scale = 1.0f / (fmaxf(sqrtf(tot), EPSN) * TEMP);

    // swizzled store: c0 = 2*tid; chunk = c0>>5; logical slot (c0>>3)&3
    const int chunk = tid >> 4;
    const int cSlot = (tid >> 2) & 3;
    const int phys = cSlot ^ ((row >> 1) & 3);
    unsigned short r0 = f2bf(a0 * scale);
    unsigned short r1 = f2bf(a1 * scale);
    unsigned int pk = (unsigned int)r0 | ((unsigned int)r1 << 16);
    *reinterpret_cast<unsigned int*>(A + (size_t)row * H_ + chunk * 32 + phys * 8 +
                                     ((tid * 2) & 7)) = pk;
    if (tid == 0) valid[row] = (cnt > 0) ? 1 : 0;
}

// ---------------------------------------------------------------------------
// Kernel 2: full-M GEMM with a NON-DRAINING pipeline (T3/T4).
// The old __syncthreads() per K-iter forced s_waitcnt vmcnt(0), draining the
// tile-(kt+1) prefetch issued ~300cyc earlier -> a full memory latency stall
// every iteration (all pipes <15%). Replaced with raw s_barrier + counted
// vmcnt so prefetch loads stay in flight across the barrier.
//
// Per iter kt (one raw barrier):
//   [A] issue B(kt+1) -> regs (4x dwordx4)
//   [B] asm vmcnt(4): A(kt)'s 5 gload_lds done, B(kt+1) stays in flight.
//       (per-wave wait BEFORE barrier => cross-wave LDS visibility after it)
//   [C] s_barrier (raw) + compiler/scheduler fence (no code motion across)
//   [D] issue A(kt+1) gload_lds -> As[cur^1]   (prev read of that buffer
//       completed before this barrier -> WAR safe with 2 buffers)
//   [E] ds_read frags (dual-swizzled, conflict-free) + 40 MFMA
//   [F] consume B regs (compiler emits vmcnt(5) -> A stays in flight):
//       en partials, cvt bf16, swizzled ds_write -> Bs[cur^1]
//   [G] asm lgkmcnt(0): ds_writes visible before the next barrier
// ---------------------------------------------------------------------------
__global__ __launch_bounds__(256, 2) void gemm_kernel(const float* __restrict__ emb,
                                                      const unsigned short* __restrict__ A,
                                                      const int* __restrict__ valid,
                                                      float* __restrict__ out) {
    const int n0 = blockIdx.x * BN;
    const int tid = threadIdx.x;
    const int wave = tid >> 6, lane = tid & 63, quad = lane >> 4, lq = lane & 15;

    __shared__ alignas(16) short As[2][BM * BK];  // 2 x 20 KB bf16 (swizzled content)
    __shared__ alignas(16) short Bs[2][BN * BK];  // 2 x  8 KB bf16 (swizzled slots)
    __shared__ float sEn[BN];
    __shared__ int sMask[B_];

    // per-session validity bitmask (20 bits)
    if (tid < B_) {
        int m = 0;
        for (int s = 0; s < S_; ++s) m |= (valid[tid * S_ + s] ? 1 : 0) << s;
        sMask[tid] = m;
    }

    // --- staging geometry ---
    // A: 5 gload_lds issues; issue i covers row tid/4 + i*64, phys slot tid&3
    // (ws is pre-swizzled by pool_kernel, so the copy stays linear).
    const unsigned short* aSrc = A + (size_t)(tid >> 2) * H_ + (tid & 3) * 8;
    // B: thread owns n-row tid>>1, 16 fp32 at cols (tid&1)*16 (+k0).
    const int brLoc = tid >> 1;
    int brGlb = n0 + brLoc;
    if (brGlb > NITEMS - 1) brGlb = NITEMS - 1;  // clamp: OOB cols computed, never stored
    const float* bSrc = emb + (size_t)brGlb * H_ + (tid & 1) * 16;
    // swizzled LDS write offsets (shorts): logical slots 2(tid&1)+{0,1} at
    // phys = q ^ ((brLoc>>1)&3)
    const int bswz = (brLoc >> 1) & 3;
    const int bw0 = brLoc * BK + ((((tid & 1) * 2) + 0) ^ bswz) * 8;
    const int bw1 = brLoc * BK + ((((tid & 1) * 2) + 1) ^ bswz) * 8;

    float rowSq = 0.f;

    // --- prologue: stage tile 0 (drained once; steady state never drains) ---
    {
        const float4 v0 = *reinterpret_cast<const float4*>(bSrc);
        const float4 v1 = *reinterpret_cast<const float4*>(bSrc + 4);
        const float4 v2 = *reinterpret_cast<const float4*>(bSrc + 8);
        const float4 v3 = *reinterpret_cast<const float4*>(bSrc + 12);
#pragma unroll
        for (int i = 0; i < 5; ++i)
            load_lds16(aSrc + i * 64 * H_, (char*)(&As[0][0]) + tid * 16 + i * 4096);
        rowSq += v0.x * v0.x + v0.y * v0.y + v0.z * v0.z + v0.w * v0.w;
        rowSq += v1.x * v1.x + v1.y * v1.y + v1.z * v1.z + v1.w * v1.w;
        rowSq += v2.x * v2.x + v2.y * v2.y + v2.z * v2.z + v2.w * v2.w;
        rowSq += v3.x * v3.x + v3.y * v3.y + v3.z * v3.z + v3.w * v3.w;
        short8 lo, hi;
        lo[0] = (short)f2bf(v0.x); lo[1] = (short)f2bf(v0.y);
        lo[2] = (short)f2bf(v0.z); lo[3] = (short)f2bf(v0.w);
        lo[4] = (short)f2bf(v1.x); lo[5] = (short)f2bf(v1.y);
        lo[6] = (short)f2bf(v1.z); lo[7] = (short)f2bf(v1.w);
        hi[0] = (short)f2bf(v2.x); hi[1] = (short)f2bf(v2.y);
        hi[2] = (short)f2bf(v2.z); hi[3] = (short)f2bf(v2.w);
        hi[4] = (short)f2bf(v3.x); hi[5] = (short)f2bf(v3.y);
        hi[6] = (short)f2bf(v3.z); hi[7] = (short)f2bf(v3.w);
        *reinterpret_cast<short8*>(&Bs[0][bw0]) = lo;
        *reinterpret_cast<short8*>(&Bs[0][bw1]) = hi;
    }
    asm volatile("s_waitcnt vmcnt(0)" ::: "memory");
    __syncthreads();

    f32x4 acc[5][8];
#pragma unroll
    for (int i = 0; i < 5; ++i)
#pragma unroll
        for (int j = 0; j < 8; ++j) acc[i][j] = (f32x4)0.f;

    const int fswz = (lq >> 1) & 3;  // frag-read slot swizzle (same for A and B)
    int cur = 0;
    for (int kt = 0; kt < NKT; ++kt) {
        const bool more = (kt + 1 < NKT);
        // [A] next B tile -> regs
        float4 v0, v1, v2, v3;
        if (more) {
            const int k0 = (kt + 1) * BK;
            v0 = *reinterpret_cast<const float4*>(bSrc + k0);
            v1 = *reinterpret_cast<const float4*>(bSrc + k0 + 4);
            v2 = *reinterpret_cast<const float4*>(bSrc + k0 + 8);
            v3 = *reinterpret_cast<const float4*>(bSrc + k0 + 12);
        }
        // [B] wait A(kt) landed; keep the 4 B loads in flight
        if (more) asm volatile("s_waitcnt vmcnt(4)" ::: "memory");
        else      asm volatile("s_waitcnt vmcnt(0)" ::: "memory");
        // [C] raw barrier; fence against any memory op crossing it
        __builtin_amdgcn_s_barrier();
        __builtin_amdgcn_sched_barrier(0);
        asm volatile("" ::: "memory");
        // [D] next A tile -> other LDS buffer (stays in flight across next barrier)
        if (more) {
            const int k0 = (kt + 1) * BK;
#pragma unroll
            for (int i = 0; i < 5; ++i)
                load_lds16(aSrc + k0 + i * 64 * H_,
                           (char*)(&As[cur ^ 1][0]) + tid * 16 + i * 4096);
        }
        // [E] fragments + MFMA
        short8 bF[8];
#pragma unroll
        for (int nf = 0; nf < 8; ++nf) {
            const int rB = nf * 16 + lq;
            bF[nf] = *reinterpret_cast<const short8*>(
                &Bs[cur][rB * BK + ((quad ^ fswz) * 8)]);
        }
#pragma unroll
        for (int mf = 0; mf < 5; ++mf) {
            const int rA = wave * 80 + mf * 16 + lq;
            const short8 aF = *reinterpret_cast<const short8*>(
                &As[cur][rA * BK + ((quad ^ fswz) * 8)]);
#pragma unroll
            for (int nf = 0; nf < 8; ++nf)
                acc[mf][nf] =
                    __builtin_amdgcn_mfma_f32_16x16x32_bf16(aF, bF[nf], acc[mf][nf], 0, 0, 0);
        }
        // [F] consume B regs: en partials + cvt + swizzled ds_write
        if (more) {
            rowSq += v0.x * v0.x + v0.y * v0.y + v0.z * v0.z + v0.w * v0.w;
            rowSq += v1.x * v1.x + v1.y * v1.y + v1.z * v1.z + v1.w * v1.w;
            rowSq += v2.x * v2.x + v2.y * v2.y + v2.z * v2.z + v2.w * v2.w;
            rowSq += v3.x * v3.x + v3.y * v3.y + v3.z * v3.z + v3.w * v3.w;
            short8 lo, hi;
            lo[0] = (short)f2bf(v0.x); lo[1] = (short)f2bf(v0.y);
            lo[2] = (short)f2bf(v0.z); lo[3] = (short)f2bf(v0.w);
            lo[4] = (short)f2bf(v1.x); lo[5] = (short)f2bf(v1.y);
            lo[6] = (short)f2bf(v1.z); lo[7] = (short)f2bf(v1.w);
            hi[0] = (short)f2bf(v2.x); hi[1] = (short)f2bf(v2.y);
            hi[2] = (short)f2bf(v2.z); hi[3] = (short)f2bf(v2.w);
            hi[4] = (short)f2bf(v3.x); hi[5] = (short)f2bf(v3.y);
            hi[6] = (short)f2bf(v3.z); hi[7] = (short)f2bf(v3.w);
            *reinterpret_cast<short8*>(&Bs[cur ^ 1][bw0]) = lo;
            *reinterpret_cast<short8*>(&Bs[cur ^ 1][bw1]) = hi;
        }
        // [G] ds_writes visible before next barrier
        asm volatile("s_waitcnt lgkmcnt(0)" ::: "memory");
        cur ^= 1;
    }

    // finalize en (two threads per row, accumulated in regs during staging)
    rowSq += __shfl_xor(rowSq, 1, 64);
    if (!(tid & 1)) sEn[brLoc] = fmaxf(sqrtf(rowSq), EPSN);
    __syncthreads();

    // epilogue: wave w owns sessions 4w..4w+3 (80 rows = exactly 4 sessions).
    // C/D layout: col = lane&15 (n), row = quad*4+e (m).
#pragma unroll
    for (int nf = 0; nf < 8; ++nf) {
        const int ncol = nf * 16 + lq;
        const int n = n0 + ncol;
        const float inv_en = 1.0f / sEn[ncol];
#pragma unroll
        for (int bl = 0; bl < 4; ++bl) {
            const int bb = wave * 4 + bl;
            const int msk = sMask[bb];
            const int rLo = bl * S_;  // local row base within this wave's 80-row slice
            float lm = -__builtin_inff();
            const int mfLo = rLo >> 4;
            const int mfHi = (rLo + S_ - 1) >> 4;
#pragma unroll
            for (int mf = mfLo; mf <= mfHi; ++mf)
#pragma unroll
                for (int e = 0; e < 4; ++e) {
                    const int r = mf * 16 + quad * 4 + e;
                    const unsigned off = (unsigned)(r - rLo);
                    const bool ok = (off < (unsigned)S_) && ((msk >> off) & 1);
                    lm = ok ? fmaxf(lm, acc[mf][nf][e]) : lm;
                }
            lm = fmaxf(lm, __shfl_xor(lm, 16, 64));
            lm = fmaxf(lm, __shfl_xor(lm, 32, 64));
            if (quad == 0 && n < NITEMS)
                out[(size_t)bb * NITEMS + n] = lm * inv_en;
        }
    }
}

extern "C" void kernel_launch(void* const* d_in, const int* in_sizes, int n_in,
                              void* d_out, int out_size, void* d_ws, size_t ws_size,
                              hipStream_t stream) {
    const float* hidden = (const float*)d_in[0];   // [16,1280,768] f32
    const float* emb    = (const float*)d_in[1];   // [50000,768] f32
    const int*   pos    = (const int*)d_in[3];     // [16,1280] i32
    float* out = (float*)d_out;                    // [16,50000] f32

    unsigned short* Abf = (unsigned short*)d_ws;               // 320*768 bf16 (swizzled)
    int* valid = (int*)((char*)d_ws + (size_t)320 * 768 * 2);  // 320 ints

    pool_kernel<<<dim3(320), dim3(384), 0, stream>>>(hidden, pos, Abf, valid);
    gemm_kernel<<<dim3((NITEMS + BN - 1) / BN), dim3(256), 0, stream>>>(emb, Abf, valid, out);
}